// Round 6
// baseline (3457.749 us; speedup 1.0000x reference)
//
#include <hip/hip_runtime.h>
#include <hip/hip_bf16.h>

// ViT-B/16 forward, MI355X. Round 8: two GEMM geometries --
//  N>=2304 (qkv, fc1): 128x256 tile, 8 waves of 64x64 (acc[4][4], FLOP/LDS-byte
//    32 vs 21), 3-deep counted-vmcnt pipeline (72KB LDS, 2 blocks/CU).
//  N==768 (patch, proj, fc2): 128x128 tile, 8 waves of 32x64, 4-deep pipeline.
// Both: global_load_lds width-16, raw s_barrier 1/K-step, XOR slot swizzle
// (bank-conflict-free, verified 0 conflicts in r7), bijective XCD swizzle.
// GELU: branch-free A&S 7.1.26 erf (|err|<=1.5e-7, ~2.5x cheaper than libm).
// MFMA attention unchanged.

#define B_     32
#define DIM_   768
#define N_     197
#define M_     (B_*N_)      // 6304
#define NP_    196
#define MP_    (B_*NP_)     // 6272
#define HEADS_ 12
#define HD_    64
#define FF_    3072
#define NRD_   732
#define QKV_   2304
#define DEPTH_ 12

typedef unsigned short u16;
typedef unsigned int   u32;
typedef __attribute__((ext_vector_type(4))) float    f32x4;
typedef __attribute__((ext_vector_type(8))) u16      ushort8;
typedef __attribute__((ext_vector_type(8))) __bf16   bf16x8;

__device__ __forceinline__ float b2f(u16 u) {
    return __builtin_bit_cast(float, ((u32)u) << 16);
}
__device__ __forceinline__ u16 f2b(float f) {  // RNE f32->bf16
    u32 u = __builtin_bit_cast(u32, f);
    u32 r = u + 0x7fffu + ((u >> 16) & 1u);
    return (u16)(r >> 16);
}
__device__ __forceinline__ float lo16(u32 v) { return __builtin_bit_cast(float, v << 16); }
__device__ __forceinline__ float hi16(u32 v) { return __builtin_bit_cast(float, v & 0xffff0000u); }

__device__ __forceinline__ f32x4 mfma16(ushort8 a, ushort8 b, f32x4 c) {
    return __builtin_amdgcn_mfma_f32_16x16x32_bf16(
        __builtin_bit_cast(bf16x8, a), __builtin_bit_cast(bf16x8, b), c, 0, 0, 0);
}

// async 16B global->LDS copy: lds base must be wave-uniform; g is per-lane.
__device__ __forceinline__ void gload16(const u16* g, u16* lds) {
    __builtin_amdgcn_global_load_lds(
        (const __attribute__((address_space(1))) void*)g,
        (__attribute__((address_space(3))) void*)lds, 16, 0, 0);
}

// erf-GELU via Abramowitz-Stegun 7.1.26 (|err(erf)| <= 1.5e-7, branch-free).
__device__ __forceinline__ float gelu_f(float x) {
    float z  = x * 0.70710678118654752f;
    float az = fabsf(z);
    float t  = 1.f / (1.f + 0.3275911f * az);
    float p  = t * (0.254829592f + t * (-0.284496736f + t * (1.421413741f +
               t * (-1.453152027f + t * 1.061405429f))));
    float er = 1.f - p * __expf(-az * az);
    er = __builtin_copysignf(er, z);
    return 0.5f * x * (1.f + er);
}

// ---------------- f32 -> bf16 converters ----------------
__global__ void cvt_k(const float* __restrict__ src, u16* __restrict__ dst, int n8) {
    int g = blockIdx.x * 256 + threadIdx.x;
    if (g >= n8) return;
    size_t o = (size_t)g * 8;
    float4 f0 = *(const float4*)(src + o);
    float4 f1 = *(const float4*)(src + o + 4);
    ushort8 r;
    r[0]=f2b(f0.x); r[1]=f2b(f0.y); r[2]=f2b(f0.z); r[3]=f2b(f0.w);
    r[4]=f2b(f1.x); r[5]=f2b(f1.y); r[6]=f2b(f1.z); r[7]=f2b(f1.w);
    *(ushort8*)(dst + o) = r;
}

// one layer's 4 weight mats -> contiguous bf16 wbuf [qkv|proj|fc1|fc2]
#define SEG0 1769472   // 2304*768
#define SEG1 589824    // 768*768
#define SEG2 2359296   // 3072*768
#define SEG3 2359296   // 768*3072
__global__ void cvt4_k(const float* __restrict__ s0, const float* __restrict__ s1,
                       const float* __restrict__ s2, const float* __restrict__ s3,
                       u16* __restrict__ dst) {
    int g = blockIdx.x * 256 + threadIdx.x;
    if (g >= (SEG0+SEG1+SEG2+SEG3)/8) return;
    size_t o = (size_t)g * 8;
    const float* src; size_t lo_;
    if (o < SEG0)             { src = s0; lo_ = o; }
    else if (o < SEG0+SEG1)   { src = s1; lo_ = o - SEG0; }
    else if (o < (size_t)SEG0+SEG1+SEG2) { src = s2; lo_ = o - SEG0 - SEG1; }
    else                      { src = s3; lo_ = o - SEG0 - SEG1 - SEG2; }
    float4 f0 = *(const float4*)(src + lo_);
    float4 f1 = *(const float4*)(src + lo_ + 4);
    ushort8 r;
    r[0]=f2b(f0.x); r[1]=f2b(f0.y); r[2]=f2b(f0.z); r[3]=f2b(f0.w);
    r[4]=f2b(f1.x); r[5]=f2b(f1.y); r[6]=f2b(f1.z); r[7]=f2b(f1.w);
    *(ushort8*)(dst + o) = r;
}

// ---------------- patchify: x[B,3,224,224] -> P bf16 [6272,768]
__global__ void patchify_k(const float* __restrict__ X, u16* __restrict__ P) {
    int idx = blockIdx.x * 256 + threadIdx.x;
    if (idx >= MP_ * DIM_) return;
    int row = idx / DIM_, k = idx - row * DIM_;
    int b = row / NP_, p = row - b * NP_;
    int gy = p / 14, gx = p - gy * 14;
    int c = k >> 8, r = k & 255;
    int py = r >> 4, px = r & 15;
    P[idx] = f2b(X[((b * 3 + c) * 224 + gy * 16 + py) * 224 + gx * 16 + px]);
}

// ---------------- tokens: f32 patch-GEMM out + cls -> h f32
__global__ void build_tokens_k(const float* __restrict__ P, const float* __restrict__ cls,
                               float* __restrict__ T) {
    int idx = blockIdx.x * 256 + threadIdx.x;
    if (idx >= M_ * DIM_) return;
    int row = idx / DIM_, c = idx - row * DIM_;
    int b = row / N_, t = row - b * N_;
    T[idx] = (t == 0) ? cls[c] : P[(size_t)(b * NP_ + t - 1) * DIM_ + c];
}

// ---------------- qkv bias for ALL layers: concat(q_bias, 0, v_bias) per layer
__global__ void qkvbias_all_k(const float* __restrict__ qb, const float* __restrict__ vb,
                              float* __restrict__ out) {
    int g = blockIdx.x * 256 + threadIdx.x;
    if (g >= DEPTH_ * QKV_) return;
    int l = g / QKV_, n = g - l * QKV_;
    out[g] = (n < DIM_) ? qb[l * DIM_ + n]
                        : (n < 2 * DIM_ ? 0.f : vb[l * DIM_ + n - 2 * DIM_]);
}

// ---------------- LayerNorm (biased var, eps=1e-5). One block(256) per row.
template <int OUTBF>
__global__ void layernorm_k(const float* __restrict__ X, const float* __restrict__ w,
                            const float* __restrict__ bta, void* __restrict__ Yv) {
    int row = blockIdx.x;
    const float* x = X + (size_t)row * DIM_;
    int t = threadIdx.x;
    float v[3]; float s = 0.f, q = 0.f;
#pragma unroll
    for (int i = 0; i < 3; i++) { float u = x[t + i * 256]; v[i] = u; s += u; q += u * u; }
#pragma unroll
    for (int off = 32; off > 0; off >>= 1) {
        s += __shfl_down(s, off, 64);
        q += __shfl_down(q, off, 64);
    }
    __shared__ float ss[4], qq[4];
    int wid = t >> 6, lane = t & 63;
    if (!lane) { ss[wid] = s; qq[wid] = q; }
    __syncthreads();
    s = ss[0] + ss[1] + ss[2] + ss[3];
    q = qq[0] + qq[1] + qq[2] + qq[3];
    float mu = s * (1.f / 768.f);
    float var = q * (1.f / 768.f) - mu * mu;
    float rs = rsqrtf(var + 1e-5f);
#pragma unroll
    for (int i = 0; i < 3; i++) {
        int c = t + i * 256;
        float o = (v[i] - mu) * rs * w[c] + bta[c];
        if (OUTBF) ((u16*)Yv)[(size_t)row * DIM_ + c] = f2b(o);
        else       ((float*)Yv)[(size_t)row * DIM_ + c] = o;
    }
}

// ---------------- MFMA NT GEMM: C[M,Nc] = A[M,K](bf16) * W[Nc,K]^T(bf16)
// BM=128 x BN_ tile, BK=32, 512 threads = 8 waves.
//   BN_=128: wave = 32x64 (MI=2), PIPE=4 buffers, 2 loads/step, vmcnt(4).
//   BN_=256: wave = 64x64 (MI=4), PIPE=3 buffers, 3 loads/step, vmcnt(3).
// Counted-vmcnt pipeline: stage tile t+PF after computing tile t, one raw
// s_barrier per K-step; prefetch stays in flight across the barrier.
// Buffer safety: stage target buf[(t+PF)%PIPE] was last computed at t-1,
// finished by all waves before barrier(t).
// XOR slot swizzle: physical slot s' of row r holds logical slot s'^((r>>1)&3)
// (global source pre-swizzled; LDS dest of global_load_lds linear; read uses
// lane-constant mirror) -> 0 bank conflicts (verified r7).
// Nc % BN_ == 0; M edge clamped on load, masked on store.
template <int ACT, int OUTBF, int BN_, int PIPE>
__launch_bounds__(512)
__global__ void gemm_bt(const u16* __restrict__ A, const u16* __restrict__ W,
                        const float* __restrict__ bias, const float* res,
                        void* Cv, int M, int Nc, int K) {
    constexpr int NWN    = BN_ / 64;    // wave col-strips (2 or 4)
    constexpr int MI     = NWN;         // m-frags per wave (2 or 4)
    constexpr int WROWS  = 16 * MI;     // rows per wave tile (32 or 64)
    constexpr int WCALLS = BN_ / 128;   // W stage calls per K-step (1 or 2)
    constexpr int PF     = PIPE - 1;    // prefetch distance
    __shared__ u16 As[PIPE][128 * 32];
    __shared__ u16 Ws[PIPE][BN_ * 32];
    const int tid = threadIdx.x;
    const int lane = tid & 63, w = tid >> 6;
    const int llo = lane & 15, lhi = lane >> 4;
    const int wn = w % NWN, wm = w / NWN;

    // bijective XCD-aware swizzle of the flat block id (m204)
    const int nwg = gridDim.x * gridDim.y;
    int bid = blockIdx.y * gridDim.x + blockIdx.x;
    {
        int q = nwg >> 3, r = nwg & 7;
        int xcd = bid & 7, idx = bid >> 3;
        bid = (xcd < r ? xcd * (q + 1) : r * (q + 1) + (xcd - r) * q) + idx;
    }
    const int m0 = (bid / gridDim.x) * 128, n0 = (bid % gridDim.x) * BN_;

    f32x4 acc[MI][4] = {};

    // staging: thread t -> physical (row tid>>2, slot tid&3); global source
    // fetches the LOGICAL slot that belongs there under the XOR swizzle.
    const int srow = tid >> 2;
    const int scol = ((tid & 3) ^ ((srow >> 1) & 3)) * 8;
    int ar = m0 + srow; if (ar >= M) ar = M - 1;
    const u16* ga = A + (size_t)ar * K + scol;
    const u16* gw = W + (size_t)(n0 + srow) * K + scol;
    const int ldso = (w * 16) * 32;   // wave-uniform LDS offset (1KB region)

    // read-side mirror XOR: fragment rows = mult16 + llo -> (row>>1)&3 ==
    // (llo>>1)&3, lane-constant (holds for W rows +128 too: 64c = 0 mod 4).
    const int rslot = (lhi ^ ((llo >> 1) & 3)) * 8;

    const int nt = K >> 5;   // BK=32

    auto stage = [&](int tt, int bb) {
        gload16(ga + (size_t)tt * 32, As[bb] + ldso);
#pragma unroll
        for (int c = 0; c < WCALLS; ++c)
            gload16(gw + (size_t)c * 128 * K + (size_t)tt * 32,
                    Ws[bb] + (c * 128 + w * 16) * 32);
    };

    // prologue: stage tiles 0..PF-1
#pragma unroll
    for (int p = 0; p < PF; ++p) stage(p, p);

    int cbuf = 0, sbuf = PF % PIPE;
    for (int t = 0; t < nt; ++t) {
        // wait for tile t only; keep PF-1 newer tiles in flight across barrier
        if constexpr (PIPE == 4) {
            if (t < nt - 2)      asm volatile("s_waitcnt vmcnt(4)" ::: "memory");
            else if (t < nt - 1) asm volatile("s_waitcnt vmcnt(2)" ::: "memory");
            else                 asm volatile("s_waitcnt vmcnt(0)" ::: "memory");
        } else {                 // PIPE == 3, 3 loads/step
            if (t < nt - 1)      asm volatile("s_waitcnt vmcnt(3)" ::: "memory");
            else                 asm volatile("s_waitcnt vmcnt(0)" ::: "memory");
        }
        __builtin_amdgcn_s_barrier();   // all waves' tile-t loads landed

        const u16* ab = As[cbuf];
        const u16* wb = Ws[cbuf];
        ushort8 af[MI], bfr[4];
#pragma unroll
        for (int mi = 0; mi < MI; mi++)
            af[mi] = *(const ushort8*)(ab + (wm * WROWS + mi * 16 + llo) * 32 + rslot);
#pragma unroll
        for (int ni = 0; ni < 4; ni++)
            bfr[ni] = *(const ushort8*)(wb + (wn * 64 + ni * 16 + llo) * 32 + rslot);
#pragma unroll
        for (int mi = 0; mi < MI; mi++)
#pragma unroll
            for (int ni = 0; ni < 4; ni++)
                acc[mi][ni] = mfma16(af[mi], bfr[ni], acc[mi][ni]);

        // stage tile t+PF into the buffer freed by compute(t-1)
        if (t + PF < nt) stage(t + PF, sbuf);
        cbuf = (cbuf + 1 == PIPE) ? 0 : cbuf + 1;
        sbuf = (sbuf + 1 == PIPE) ? 0 : sbuf + 1;
    }

    // epilogue: D(row,col): row = quad*4+reg, col = lane&15 (m89-verified)
    const int cb = n0 + wn * 64 + llo;
    const int rb = m0 + wm * WROWS + lhi * 4;
#pragma unroll
    for (int ni = 0; ni < 4; ni++) {
        int col = cb + ni * 16;
        float bv = bias ? bias[col] : 0.f;
#pragma unroll
        for (int mi = 0; mi < MI; mi++) {
#pragma unroll
            for (int rg = 0; rg < 4; rg++) {
                int row = rb + mi * 16 + rg;
                if (row >= M) continue;
                float t = acc[mi][ni][rg] + bv;
                if (ACT) t = gelu_f(t);
                if (res) t += res[(size_t)row * Nc + col];
                if (OUTBF) ((u16*)Cv)[(size_t)row * Nc + col] = f2b(t);
                else       ((float*)Cv)[(size_t)row * Nc + col] = t;
            }
        }
    }
}

// ---------------- fused MFMA attention (unchanged).
__device__ __forceinline__ int vswz(int d) {
    return ((d & 7) ^ ((d >> 3) & 7)) << 3;
}

__launch_bounds__(256)
__global__ void attn3_k(const u16* __restrict__ qkv, const float* __restrict__ rpt,
                        u16* __restrict__ O) {
    __shared__ u16 smem[16128 + 16384];          // 63.5 KB
    u16* Ks = smem;                              // [224][72]
    u16* Vt = smem + 16128;                      // [64][256] swizzled
    u16* Ps = smem;                              // [64][232], aliases Ks
    const int b = blockIdx.x / HEADS_, hh = blockIdx.x % HEADS_;
    const int i0 = blockIdx.y * 64;
    const int t = threadIdx.x;
    const int w = t >> 6, lane = t & 63;
    const int lhi = lane >> 4, llo = lane & 15;
    const size_t base = (size_t)b * N_ * QKV_ + (size_t)hh * HD_;
    const int iw = i0 + w * 16;

    int qrow = iw + llo; if (qrow > 196) qrow = 196;
    const ushort8 af0 = *(const ushort8*)(qkv + base + (size_t)qrow * QKV_ + lhi * 8);
    const ushort8 af1 = *(const ushort8*)(qkv + base + (size_t)qrow * QKV_ + 32 + lhi * 8);

    for (int g = t; g < 1576; g += 256) {
        int j = g >> 3, d0 = (g & 7) * 8;
        ushort8 kv = *(const ushort8*)(qkv + base + (size_t)j * QKV_ + 768 + d0);
        *(ushort8*)(Ks + j * 72 + d0) = kv;
        ushort8 vv = *(const ushort8*)(qkv + base + (size_t)j * QKV_ + 1536 + d0);
#pragma unroll
        for (int e = 0; e < 8; e++) {
            int d = d0 + e;
            Vt[d * 256 + (j ^ vswz(d))] = ((const u16*)&vv)[e];
        }
    }
    if (t < 216) {
        int j = 197 + (t >> 3), d0 = (t & 7) * 8;
        *(uint4*)(Ks + j * 72 + d0) = make_uint4(0u, 0u, 0u, 0u);
    }
    for (int g = t; g < 1728; g += 256) {
        int d = g / 27, c = 197 + (g - d * 27);
        Vt[d * 256 + (c ^ vswz(d))] = 0;
    }
    __syncthreads();

    const bool wvalid = (iw <= 196);
    f32x4 acc[14] = {};
    float mx[4], sum[4];

    if (wvalid) {
#pragma unroll
        for (int jt = 0; jt < 14; jt++) {
            const u16* kp = Ks + (jt * 16 + llo) * 72 + lhi * 8;
            ushort8 b0 = *(const ushort8*)(kp);
            ushort8 b1 = *(const ushort8*)(kp + 32);
            acc[jt] = mfma16(af0, b0, acc[jt]);
            acc[jt] = mfma16(af1, b1, acc[jt]);
        }
        int iy4[4], ix4[4]; bool icls[4];
#pragma unroll
        for (int rg = 0; rg < 4; rg++) {
            int i = iw + lhi * 4 + rg; if (i > 196) i = 196;
            icls[rg] = (i == 0);
            int pi = i - 1;
            iy4[rg] = pi / 14; ix4[rg] = pi - iy4[rg] * 14;
            mx[rg] = -INFINITY;
        }
#pragma unroll
        for (int jt = 0; jt < 14; jt++) {
            int j = jt * 16 + llo;
            if (j <= 196) {
                bool jcls = (j == 0);
                int pj = j - 1;
                int jy = pj / 14, jx = pj - jy * 14;
#pragma unroll
                for (int rg = 0; rg < 4; rg++) {
                    int idx;
                    if (icls[rg])  idx = jcls ? (NRD_ - 1) : (NRD_ - 3);
                    else if (jcls) idx = NRD_ - 2;
                    else           idx = (iy4[rg] - jy + 13) * 27 + (ix4[rg] - jx + 13);
                    float sv = acc[jt][rg] * 0.125f + rpt[idx * HEADS_ + hh];
                    acc[jt][rg] = sv;
                    mx[rg] = fmaxf(mx[rg], sv);
                }
            } else {
#pragma unroll
                for (int rg = 0; rg < 4; rg++) acc[jt][rg] = -INFINITY;
            }
        }
#pragma unroll
        for (int rg = 0; rg < 4; rg++) {
#pragma unroll
            for (int off = 1; off < 16; off <<= 1)
                mx[rg] = fmaxf(mx[rg], __shfl_xor(mx[rg], off, 64));
            sum[rg] = 0.f;
        }
#pragma unroll
        for (int jt = 0; jt < 14; jt++)
#pragma unroll
            for (int rg = 0; rg < 4; rg++) {
                float ev = __expf(acc[jt][rg] - mx[rg]);
                acc[jt][rg] = ev;
                sum[rg] += ev;
            }
#pragma unroll
        for (int rg = 0; rg < 4; rg++) {
#pragma unroll
            for (int off = 1; off < 16; off <<= 1)
                sum[rg] += __shfl_xor(sum[rg], off, 64);
            sum[rg] = 1.f / sum[rg];
        }
#pragma unroll
        for (int jt = 0; jt < 14; jt++)
#pragma unroll
            for (int rg = 0; rg < 4; rg++) acc[jt][rg] *= sum[rg];
    }
    __syncthreads();   // all Ks reads done -> Ps may overwrite

    if (wvalid) {
#pragma unroll
        for (int jt = 0; jt < 14; jt++)
#pragma unroll
            for (int rg = 0; rg < 4; rg++)
                Ps[(w * 16 + lhi * 4 + rg) * 232 + jt * 16 + llo] = f2b(acc[jt][rg]);
        f32x4 o[4] = {};
#pragma unroll
        for (int jk = 0; jk < 7; jk++) {
            ushort8 pa = *(const ushort8*)(Ps + (w * 16 + llo) * 232 + jk * 32 + lhi * 8);
#pragma unroll
            for (int dt = 0; dt < 4; dt++) {
                int d = dt * 16 + llo;
                ushort8 vf = *(const ushort8*)(Vt + d * 256 + ((jk * 32 + lhi * 8) ^ vswz(d)));
                o[dt] = mfma16(pa, vf, o[dt]);
            }
        }
#pragma unroll
        for (int dt = 0; dt < 4; dt++)
#pragma unroll
            for (int rg = 0; rg < 4; rg++) {
                int i = iw + lhi * 4 + rg;
                if (i <= 196)
                    O[(size_t)(b * N_ + i) * DIM_ + hh * HD_ + dt * 16 + llo] = f2b(o[dt][rg]);
            }
    }
}

extern "C" void kernel_launch(void* const* d_in, const int* in_sizes, int n_in,
                              void* d_out, int out_size, void* d_ws, size_t ws_size,
                              hipStream_t stream) {
    (void)in_sizes; (void)n_in; (void)out_size; (void)ws_size;
    const float* x    = (const float*)d_in[0];
    const float* pew  = (const float*)d_in[1];
    const float* peb  = (const float*)d_in[2];
    const float* cls  = (const float*)d_in[3];
    const float* n1w  = (const float*)d_in[4];
    const float* n1b  = (const float*)d_in[5];
    const float* qkvw = (const float*)d_in[6];
    const float* qb   = (const float*)d_in[7];
    const float* vb   = (const float*)d_in[8];
    const float* rpt  = (const float*)d_in[9];
    const float* pw   = (const float*)d_in[10];
    const float* pb   = (const float*)d_in[11];
    const float* n2w  = (const float*)d_in[12];
    const float* n2b  = (const float*)d_in[13];
    const float* f1w  = (const float*)d_in[14];
    const float* f1b  = (const float*)d_in[15];
    const float* f2w  = (const float*)d_in[16];
    const float* f2b_ = (const float*)d_in[17];
    const float* nfw  = (const float*)d_in[18];
    const float* nfb  = (const float*)d_in[19];

    // workspace (floats): h | y(bf16) | un | wbuf(bf16) | qbias[12]  ~= 82 MB
    float* ws = (float*)d_ws;
    float* h     = ws;                                   // 4,841,472 f32
    u16*   y     = (u16*)(ws + 4841472);                 // bf16 [M,768]
    float* un    = ws + 4841472 + 2420736;               // 9,682,944 f32 union
    u16*   wbuf  = (u16*)(un + 9682944);                 // 7,077,888 bf16
    float* qbias = (float*)(wbuf + 7077888);             // 12*2304 f32
    u16*   qkvb   = (u16*)un;                            // bf16 [M,2304]
    u16*   hidden = (u16*)un;                            // bf16 [M,3072]
    u16*   pmat   = (u16*)un;                            // bf16 [6272,768]
    float* pout   = un + 4816896;                        // f32  [6272,768]

    const int MT = (M_ + 127) / 128;  // 50

    // patch embed
    cvt_k<<<288, 256, 0, stream>>>(pew, wbuf, SEG1 / 8);
    patchify_k<<<(MP_ * DIM_ + 255) / 256, 256, 0, stream>>>(x, pmat);
    qkvbias_all_k<<<(DEPTH_ * QKV_ + 255) / 256, 256, 0, stream>>>(qb, vb, qbias);
    gemm_bt<0, 0, 128, 4><<<dim3(6, 49), 512, 0, stream>>>(pmat, wbuf, peb, nullptr, pout,
                                                           MP_, DIM_, DIM_);
    build_tokens_k<<<(M_ * DIM_ + 255) / 256, 256, 0, stream>>>(pout, cls, h);

    for (int l = 0; l < 12; l++) {
        layernorm_k<1><<<M_, 256, 0, stream>>>(h, n1w + l * DIM_, n1b + l * DIM_, y);
        cvt4_k<<<3456, 256, 0, stream>>>(qkvw + (size_t)l * SEG0, pw + (size_t)l * SEG1,
                                         f1w + (size_t)l * SEG2, f2w + (size_t)l * SEG3, wbuf);
        gemm_bt<0, 1, 256, 3><<<dim3(9, MT), 512, 0, stream>>>(y, wbuf, qbias + l * QKV_,
                                                               nullptr, qkvb, M_, QKV_, DIM_);
        attn3_k<<<dim3(384, 4), 256, 0, stream>>>(qkvb, rpt + (size_t)l * NRD_ * HEADS_, y);
        gemm_bt<0, 0, 128, 4><<<dim3(6, MT), 512, 0, stream>>>(y, wbuf + SEG0, pb + l * DIM_,
                                                               h, h, M_, DIM_, DIM_);
        layernorm_k<1><<<M_, 256, 0, stream>>>(h, n2w + l * DIM_, n2b + l * DIM_, y);
        gemm_bt<1, 1, 256, 3><<<dim3(12, MT), 512, 0, stream>>>(y, wbuf + SEG0 + SEG1,
                                                                f1b + l * FF_, nullptr,
                                                                hidden, M_, FF_, DIM_);
        gemm_bt<0, 0, 128, 4><<<dim3(6, MT), 512, 0, stream>>>(hidden, wbuf + SEG0 + SEG1 + SEG2,
                                                               f2b_ + l * DIM_, h, h,
                                                               M_, DIM_, FF_);
    }
    layernorm_k<0><<<M_, 256, 0, stream>>>(h, nfw, nfb, d_out);
}

// Round 7
// 2940.405 us; speedup vs baseline: 1.1759x; 1.1759x over previous
//
#include <hip/hip_runtime.h>
#include <hip/hip_bf16.h>

// ViT-B/16 forward, MI355X. Round 9: GEMM = 128x128, BK=32, 8 waves,
// PIPE=3 counted-vmcnt pipeline at 48KB LDS -> 3 blocks/CU (24 waves/CU,
// the m97 TLP regime). Coalesced epilogue via LDS f32 bounce (two 64-col
// halves): vectorized ushort8/float4 stores + float4 res reads -- kills the
// 1.3-1.9x write amplification of the scalar u16 stores. XOR slot swizzle
// (0 bank conflicts, verified), bijective XCD swizzle, A&S GELU.
// MFMA attention unchanged.

#define B_     32
#define DIM_   768
#define N_     197
#define M_     (B_*N_)      // 6304
#define NP_    196
#define MP_    (B_*NP_)     // 6272
#define HEADS_ 12
#define HD_    64
#define FF_    3072
#define NRD_   732
#define QKV_   2304
#define DEPTH_ 12

typedef unsigned short u16;
typedef unsigned int   u32;
typedef __attribute__((ext_vector_type(4))) float    f32x4;
typedef __attribute__((ext_vector_type(8))) u16      ushort8;
typedef __attribute__((ext_vector_type(8))) __bf16   bf16x8;

__device__ __forceinline__ float b2f(u16 u) {
    return __builtin_bit_cast(float, ((u32)u) << 16);
}
__device__ __forceinline__ u16 f2b(float f) {  // RNE f32->bf16
    u32 u = __builtin_bit_cast(u32, f);
    u32 r = u + 0x7fffu + ((u >> 16) & 1u);
    return (u16)(r >> 16);
}
__device__ __forceinline__ float lo16(u32 v) { return __builtin_bit_cast(float, v << 16); }
__device__ __forceinline__ float hi16(u32 v) { return __builtin_bit_cast(float, v & 0xffff0000u); }

__device__ __forceinline__ f32x4 mfma16(ushort8 a, ushort8 b, f32x4 c) {
    return __builtin_amdgcn_mfma_f32_16x16x32_bf16(
        __builtin_bit_cast(bf16x8, a), __builtin_bit_cast(bf16x8, b), c, 0, 0, 0);
}

// async 16B global->LDS copy: lds base must be wave-uniform; g is per-lane.
__device__ __forceinline__ void gload16(const u16* g, u16* lds) {
    __builtin_amdgcn_global_load_lds(
        (const __attribute__((address_space(1))) void*)g,
        (__attribute__((address_space(3))) void*)lds, 16, 0, 0);
}

// erf-GELU via Abramowitz-Stegun 7.1.26 (|err(erf)| <= 1.5e-7, branch-free).
__device__ __forceinline__ float gelu_f(float x) {
    float z  = x * 0.70710678118654752f;
    float az = fabsf(z);
    float t  = 1.f / (1.f + 0.3275911f * az);
    float p  = t * (0.254829592f + t * (-0.284496736f + t * (1.421413741f +
               t * (-1.453152027f + t * 1.061405429f))));
    float er = 1.f - p * __expf(-az * az);
    er = __builtin_copysignf(er, z);
    return 0.5f * x * (1.f + er);
}

// ---------------- f32 -> bf16 converters ----------------
__global__ void cvt_k(const float* __restrict__ src, u16* __restrict__ dst, int n8) {
    int g = blockIdx.x * 256 + threadIdx.x;
    if (g >= n8) return;
    size_t o = (size_t)g * 8;
    float4 f0 = *(const float4*)(src + o);
    float4 f1 = *(const float4*)(src + o + 4);
    ushort8 r;
    r[0]=f2b(f0.x); r[1]=f2b(f0.y); r[2]=f2b(f0.z); r[3]=f2b(f0.w);
    r[4]=f2b(f1.x); r[5]=f2b(f1.y); r[6]=f2b(f1.z); r[7]=f2b(f1.w);
    *(ushort8*)(dst + o) = r;
}

// one layer's 4 weight mats -> contiguous bf16 wbuf [qkv|proj|fc1|fc2]
#define SEG0 1769472   // 2304*768
#define SEG1 589824    // 768*768
#define SEG2 2359296   // 3072*768
#define SEG3 2359296   // 768*3072
__global__ void cvt4_k(const float* __restrict__ s0, const float* __restrict__ s1,
                       const float* __restrict__ s2, const float* __restrict__ s3,
                       u16* __restrict__ dst) {
    int g = blockIdx.x * 256 + threadIdx.x;
    if (g >= (SEG0+SEG1+SEG2+SEG3)/8) return;
    size_t o = (size_t)g * 8;
    const float* src; size_t lo_;
    if (o < SEG0)             { src = s0; lo_ = o; }
    else if (o < SEG0+SEG1)   { src = s1; lo_ = o - SEG0; }
    else if (o < (size_t)SEG0+SEG1+SEG2) { src = s2; lo_ = o - SEG0 - SEG1; }
    else                      { src = s3; lo_ = o - SEG0 - SEG1 - SEG2; }
    float4 f0 = *(const float4*)(src + lo_);
    float4 f1 = *(const float4*)(src + lo_ + 4);
    ushort8 r;
    r[0]=f2b(f0.x); r[1]=f2b(f0.y); r[2]=f2b(f0.z); r[3]=f2b(f0.w);
    r[4]=f2b(f1.x); r[5]=f2b(f1.y); r[6]=f2b(f1.z); r[7]=f2b(f1.w);
    *(ushort8*)(dst + o) = r;
}

// ---------------- patchify: x[B,3,224,224] -> P bf16 [6272,768]
__global__ void patchify_k(const float* __restrict__ X, u16* __restrict__ P) {
    int idx = blockIdx.x * 256 + threadIdx.x;
    if (idx >= MP_ * DIM_) return;
    int row = idx / DIM_, k = idx - row * DIM_;
    int b = row / NP_, p = row - b * NP_;
    int gy = p / 14, gx = p - gy * 14;
    int c = k >> 8, r = k & 255;
    int py = r >> 4, px = r & 15;
    P[idx] = f2b(X[((b * 3 + c) * 224 + gy * 16 + py) * 224 + gx * 16 + px]);
}

// ---------------- tokens: f32 patch-GEMM out + cls -> h f32
__global__ void build_tokens_k(const float* __restrict__ P, const float* __restrict__ cls,
                               float* __restrict__ T) {
    int idx = blockIdx.x * 256 + threadIdx.x;
    if (idx >= M_ * DIM_) return;
    int row = idx / DIM_, c = idx - row * DIM_;
    int b = row / N_, t = row - b * N_;
    T[idx] = (t == 0) ? cls[c] : P[(size_t)(b * NP_ + t - 1) * DIM_ + c];
}

// ---------------- qkv bias for ALL layers: concat(q_bias, 0, v_bias) per layer
__global__ void qkvbias_all_k(const float* __restrict__ qb, const float* __restrict__ vb,
                              float* __restrict__ out) {
    int g = blockIdx.x * 256 + threadIdx.x;
    if (g >= DEPTH_ * QKV_) return;
    int l = g / QKV_, n = g - l * QKV_;
    out[g] = (n < DIM_) ? qb[l * DIM_ + n]
                        : (n < 2 * DIM_ ? 0.f : vb[l * DIM_ + n - 2 * DIM_]);
}

// ---------------- LayerNorm (biased var, eps=1e-5). One block(256) per row.
template <int OUTBF>
__global__ void layernorm_k(const float* __restrict__ X, const float* __restrict__ w,
                            const float* __restrict__ bta, void* __restrict__ Yv) {
    int row = blockIdx.x;
    const float* x = X + (size_t)row * DIM_;
    int t = threadIdx.x;
    float v[3]; float s = 0.f, q = 0.f;
#pragma unroll
    for (int i = 0; i < 3; i++) { float u = x[t + i * 256]; v[i] = u; s += u; q += u * u; }
#pragma unroll
    for (int off = 32; off > 0; off >>= 1) {
        s += __shfl_down(s, off, 64);
        q += __shfl_down(q, off, 64);
    }
    __shared__ float ss[4], qq[4];
    int wid = t >> 6, lane = t & 63;
    if (!lane) { ss[wid] = s; qq[wid] = q; }
    __syncthreads();
    s = ss[0] + ss[1] + ss[2] + ss[3];
    q = qq[0] + qq[1] + qq[2] + qq[3];
    float mu = s * (1.f / 768.f);
    float var = q * (1.f / 768.f) - mu * mu;
    float rs = rsqrtf(var + 1e-5f);
#pragma unroll
    for (int i = 0; i < 3; i++) {
        int c = t + i * 256;
        float o = (v[i] - mu) * rs * w[c] + bta[c];
        if (OUTBF) ((u16*)Yv)[(size_t)row * DIM_ + c] = f2b(o);
        else       ((float*)Yv)[(size_t)row * DIM_ + c] = o;
    }
}

// ---------------- MFMA NT GEMM: C[M,Nc] = A[M,K](bf16) * W[Nc,K]^T(bf16)
// 128x128 tile, BK=32, 512 threads = 8 waves of 32x64 (acc[2][4]).
// PIPE=3 counted-vmcnt pipeline: stage tile t+2 after computing tile t, one
// raw s_barrier per K-step, steady-state s_waitcnt vmcnt(2) (tile t+1 stays
// in flight across the barrier). 48KB LDS -> 3 blocks/CU (24 waves/CU).
// Buffer safety: stage target buf[(t+2)%3] was last computed at t-1, finished
// by all waves before barrier(t).
// XOR slot swizzle: physical slot s' of row r holds logical slot s'^((r>>1)&3)
// (global source pre-swizzled, LDS dest linear, lane-constant mirror on read)
// -> 0 bank conflicts (verified r7).
// Epilogue: acc -> LDS f32 bounce (two 64-col halves, stride 68 f32 =
// 16B-aligned rows, ~2-way banks) -> vectorized ushort8/float4 stores with
// float4 res reads. Nc % 128 == 0; M edge clamped on load, masked on store.
template <int ACT, int OUTBF>   // ACT: erf-GELU; OUTBF: store bf16 else f32
__launch_bounds__(512, 6)
__global__ void gemm_bt(const u16* __restrict__ A, const u16* __restrict__ W,
                        const float* __restrict__ bias, const float* res,
                        void* Cv, int M, int Nc, int K) {
    __shared__ __align__(16) u16 smem[6 * 4096];   // As[3][4096] | Ws[3][4096] = 48KB
    u16* As = smem;
    u16* Ws = smem + 3 * 4096;
    const int tid = threadIdx.x;
    const int lane = tid & 63, w = tid >> 6;
    const int llo = lane & 15, lhi = lane >> 4;
    const int wn = w & 1, wm = w >> 1;     // wave = rows wm*32..+31, cols wn*64..+63

    // bijective XCD-aware swizzle of the flat block id (m204)
    const int nwg = gridDim.x * gridDim.y;
    int bid = blockIdx.y * gridDim.x + blockIdx.x;
    {
        int q = nwg >> 3, r = nwg & 7;
        int xcd = bid & 7, idx = bid >> 3;
        bid = (xcd < r ? xcd * (q + 1) : r * (q + 1) + (xcd - r) * q) + idx;
    }
    const int m0 = (bid / gridDim.x) * 128, n0 = (bid % gridDim.x) * 128;

    f32x4 acc[2][4] = {};

    // staging: thread t -> physical (row tid>>2, slot tid&3); global source
    // fetches the LOGICAL slot that belongs there under the XOR swizzle.
    const int srow = tid >> 2;
    const int scol = ((tid & 3) ^ ((srow >> 1) & 3)) * 8;
    int ar = m0 + srow; if (ar >= M) ar = M - 1;
    const u16* ga = A + (size_t)ar * K + scol;
    const u16* gw = W + (size_t)(n0 + srow) * K + scol;
    const int ldso = (w * 16) * 32;   // wave-uniform LDS offset (1KB region)

    // read-side mirror XOR: fragment rows = mult16 + llo -> (row>>1)&3 ==
    // (llo>>1)&3, lane-constant.
    const int rslot = (lhi ^ ((llo >> 1) & 3)) * 8;

    const int nt = K >> 5;   // BK=32

    // prologue: stage tiles 0,1 into bufs 0,1 (4 loads in flight)
    gload16(ga,      As + ldso);
    gload16(gw,      Ws + ldso);
    gload16(ga + 32, As + 4096 + ldso);
    gload16(gw + 32, Ws + 4096 + ldso);

    int cbuf = 0, sbuf = 2;
    for (int t = 0; t < nt; ++t) {
        // wait for tile t only; tile t+1 stays in flight across the barrier
        if (t < nt - 1) asm volatile("s_waitcnt vmcnt(2)" ::: "memory");
        else            asm volatile("s_waitcnt vmcnt(0)" ::: "memory");
        __builtin_amdgcn_s_barrier();   // all waves' tile-t loads landed

        const u16* ab = As + cbuf * 4096;
        const u16* wb = Ws + cbuf * 4096;
        ushort8 af[2], bfr[4];
#pragma unroll
        for (int mi = 0; mi < 2; mi++)
            af[mi] = *(const ushort8*)(ab + (wm * 32 + mi * 16 + llo) * 32 + rslot);
#pragma unroll
        for (int ni = 0; ni < 4; ni++)
            bfr[ni] = *(const ushort8*)(wb + (wn * 64 + ni * 16 + llo) * 32 + rslot);
#pragma unroll
        for (int mi = 0; mi < 2; mi++)
#pragma unroll
            for (int ni = 0; ni < 4; ni++)
                acc[mi][ni] = mfma16(af[mi], bfr[ni], acc[mi][ni]);

        // stage tile t+2 into the buffer freed by compute(t-1)
        if (t + 2 < nt) {
            gload16(ga + (size_t)(t + 2) * 32, As + sbuf * 4096 + ldso);
            gload16(gw + (size_t)(t + 2) * 32, Ws + sbuf * 4096 + ldso);
        }
        cbuf = (cbuf + 1 == 3) ? 0 : cbuf + 1;
        sbuf = (sbuf + 1 == 3) ? 0 : sbuf + 1;
    }

    // ---- coalesced epilogue: LDS f32 bounce, two 64-col halves ----
    // m89 layout: acc[mi][ni][rg] = C(wm*32+mi*16+lhi*4+rg, wn*64+ni*16+llo).
    __syncthreads();                     // staging LDS dead
    float* eb = (float*)smem;            // [128][68] f32 = 34816 B (<= 48KB)
#pragma unroll
    for (int half = 0; half < 2; ++half) {
        if (wn == half) {
#pragma unroll
            for (int mi = 0; mi < 2; mi++)
#pragma unroll
                for (int ni = 0; ni < 4; ni++)
#pragma unroll
                    for (int rg = 0; rg < 4; rg++)
                        eb[(wm * 32 + mi * 16 + lhi * 4 + rg) * 68 + ni * 16 + llo] =
                            acc[mi][ni][rg];
        }
        __syncthreads();
        if (OUTBF) {
#pragma unroll
            for (int i = 0; i < 2; ++i) {
                int idx = tid + i * 512;          // 0..1023
                int row = idx >> 3, c8 = (idx & 7) * 8;
                int grow = m0 + row, gcol = n0 + half * 64 + c8;
                f32x4 v0 = *(const f32x4*)(eb + row * 68 + c8);
                f32x4 v1 = *(const f32x4*)(eb + row * 68 + c8 + 4);
                if (grow < M) {
                    float4 b0 = *(const float4*)(bias + gcol);
                    float4 b1 = *(const float4*)(bias + gcol + 4);
                    float o0[4] = {v0[0]+b0.x, v0[1]+b0.y, v0[2]+b0.z, v0[3]+b0.w};
                    float o1[4] = {v1[0]+b1.x, v1[1]+b1.y, v1[2]+b1.z, v1[3]+b1.w};
                    ushort8 r;
#pragma unroll
                    for (int j = 0; j < 4; j++) {
                        float a0 = ACT ? gelu_f(o0[j]) : o0[j];
                        float a1 = ACT ? gelu_f(o1[j]) : o1[j];
                        r[j] = f2b(a0); r[4 + j] = f2b(a1);
                    }
                    *(ushort8*)((u16*)Cv + (size_t)grow * Nc + gcol) = r;
                }
            }
        } else {
#pragma unroll
            for (int i = 0; i < 4; ++i) {
                int idx = tid + i * 512;          // 0..2047
                int row = idx >> 4, c4 = (idx & 15) * 4;
                int grow = m0 + row, gcol = n0 + half * 64 + c4;
                f32x4 v = *(const f32x4*)(eb + row * 68 + c4);
                if (grow < M) {
                    float4 bv = *(const float4*)(bias + gcol);
                    float4 o;
                    o.x = v[0] + bv.x; o.y = v[1] + bv.y;
                    o.z = v[2] + bv.z; o.w = v[3] + bv.w;
                    if (ACT) { o.x = gelu_f(o.x); o.y = gelu_f(o.y);
                               o.z = gelu_f(o.z); o.w = gelu_f(o.w); }
                    if (res) {
                        float4 rv = *(const float4*)(res + (size_t)grow * Nc + gcol);
                        o.x += rv.x; o.y += rv.y; o.z += rv.z; o.w += rv.w;
                    }
                    *(float4*)((float*)Cv + (size_t)grow * Nc + gcol) = o;
                }
            }
        }
        __syncthreads();   // eb reads done before next half's writes
    }
}

// ---------------- fused MFMA attention (unchanged).
__device__ __forceinline__ int vswz(int d) {
    return ((d & 7) ^ ((d >> 3) & 7)) << 3;
}

__launch_bounds__(256)
__global__ void attn3_k(const u16* __restrict__ qkv, const float* __restrict__ rpt,
                        u16* __restrict__ O) {
    __shared__ u16 smem[16128 + 16384];          // 63.5 KB
    u16* Ks = smem;                              // [224][72]
    u16* Vt = smem + 16128;                      // [64][256] swizzled
    u16* Ps = smem;                              // [64][232], aliases Ks
    const int b = blockIdx.x / HEADS_, hh = blockIdx.x % HEADS_;
    const int i0 = blockIdx.y * 64;
    const int t = threadIdx.x;
    const int w = t >> 6, lane = t & 63;
    const int lhi = lane >> 4, llo = lane & 15;
    const size_t base = (size_t)b * N_ * QKV_ + (size_t)hh * HD_;
    const int iw = i0 + w * 16;

    int qrow = iw + llo; if (qrow > 196) qrow = 196;
    const ushort8 af0 = *(const ushort8*)(qkv + base + (size_t)qrow * QKV_ + lhi * 8);
    const ushort8 af1 = *(const ushort8*)(qkv + base + (size_t)qrow * QKV_ + 32 + lhi * 8);

    for (int g = t; g < 1576; g += 256) {
        int j = g >> 3, d0 = (g & 7) * 8;
        ushort8 kv = *(const ushort8*)(qkv + base + (size_t)j * QKV_ + 768 + d0);
        *(ushort8*)(Ks + j * 72 + d0) = kv;
        ushort8 vv = *(const ushort8*)(qkv + base + (size_t)j * QKV_ + 1536 + d0);
#pragma unroll
        for (int e = 0; e < 8; e++) {
            int d = d0 + e;
            Vt[d * 256 + (j ^ vswz(d))] = ((const u16*)&vv)[e];
        }
    }
    if (t < 216) {
        int j = 197 + (t >> 3), d0 = (t & 7) * 8;
        *(uint4*)(Ks + j * 72 + d0) = make_uint4(0u, 0u, 0u, 0u);
    }
    for (int g = t; g < 1728; g += 256) {
        int d = g / 27, c = 197 + (g - d * 27);
        Vt[d * 256 + (c ^ vswz(d))] = 0;
    }
    __syncthreads();

    const bool wvalid = (iw <= 196);
    f32x4 acc[14] = {};
    float mx[4], sum[4];

    if (wvalid) {
#pragma unroll
        for (int jt = 0; jt < 14; jt++) {
            const u16* kp = Ks + (jt * 16 + llo) * 72 + lhi * 8;
            ushort8 b0 = *(const ushort8*)(kp);
            ushort8 b1 = *(const ushort8*)(kp + 32);
            acc[jt] = mfma16(af0, b0, acc[jt]);
            acc[jt] = mfma16(af1, b1, acc[jt]);
        }
        int iy4[4], ix4[4]; bool icls[4];
#pragma unroll
        for (int rg = 0; rg < 4; rg++) {
            int i = iw + lhi * 4 + rg; if (i > 196) i = 196;
            icls[rg] = (i == 0);
            int pi = i - 1;
            iy4[rg] = pi / 14; ix4[rg] = pi - iy4[rg] * 14;
            mx[rg] = -INFINITY;
        }
#pragma unroll
        for (int jt = 0; jt < 14; jt++) {
            int j = jt * 16 + llo;
            if (j <= 196) {
                bool jcls = (j == 0);
                int pj = j - 1;
                int jy = pj / 14, jx = pj - jy * 14;
#pragma unroll
                for (int rg = 0; rg < 4; rg++) {
                    int idx;
                    if (icls[rg])  idx = jcls ? (NRD_ - 1) : (NRD_ - 3);
                    else if (jcls) idx = NRD_ - 2;
                    else           idx = (iy4[rg] - jy + 13) * 27 + (ix4[rg] - jx + 13);
                    float sv = acc[jt][rg] * 0.125f + rpt[idx * HEADS_ + hh];
                    acc[jt][rg] = sv;
                    mx[rg] = fmaxf(mx[rg], sv);
                }
            } else {
#pragma unroll
                for (int rg = 0; rg < 4; rg++) acc[jt][rg] = -INFINITY;
            }
        }
#pragma unroll
        for (int rg = 0; rg < 4; rg++) {
#pragma unroll
            for (int off = 1; off < 16; off <<= 1)
                mx[rg] = fmaxf(mx[rg], __shfl_xor(mx[rg], off, 64));
            sum[rg] = 0.f;
        }
#pragma unroll
        for (int jt = 0; jt < 14; jt++)
#pragma unroll
            for (int rg = 0; rg < 4; rg++) {
                float ev = __expf(acc[jt][rg] - mx[rg]);
                acc[jt][rg] = ev;
                sum[rg] += ev;
            }
#pragma unroll
        for (int rg = 0; rg < 4; rg++) {
#pragma unroll
            for (int off = 1; off < 16; off <<= 1)
                sum[rg] += __shfl_xor(sum[rg], off, 64);
            sum[rg] = 1.f / sum[rg];
        }
#pragma unroll
        for (int jt = 0; jt < 14; jt++)
#pragma unroll
            for (int rg = 0; rg < 4; rg++) acc[jt][rg] *= sum[rg];
    }
    __syncthreads();   // all Ks reads done -> Ps may overwrite

    if (wvalid) {
#pragma unroll
        for (int jt = 0; jt < 14; jt++)
#pragma unroll
            for (int rg = 0; rg < 4; rg++)
                Ps[(w * 16 + lhi * 4 + rg) * 232 + jt * 16 + llo] = f2b(acc[jt][rg]);
        f32x4 o[4] = {};
#pragma unroll
        for (int jk = 0; jk < 7; jk++) {
            ushort8 pa = *(const ushort8*)(Ps + (w * 16 + llo) * 232 + jk * 32 + lhi * 8);
#pragma unroll
            for (int dt = 0; dt < 4; dt++) {
                int d = dt * 16 + llo;
                ushort8 vf = *(const ushort8*)(Vt + d * 256 + ((jk * 32 + lhi * 8) ^ vswz(d)));
                o[dt] = mfma16(pa, vf, o[dt]);
            }
        }
#pragma unroll
        for (int dt = 0; dt < 4; dt++)
#pragma unroll
            for (int rg = 0; rg < 4; rg++) {
                int i = iw + lhi * 4 + rg;
                if (i <= 196)
                    O[(size_t)(b * N_ + i) * DIM_ + hh * HD_ + dt * 16 + llo] = f2b(o[dt][rg]);
            }
    }
}

extern "C" void kernel_launch(void* const* d_in, const int* in_sizes, int n_in,
                              void* d_out, int out_size, void* d_ws, size_t ws_size,
                              hipStream_t stream) {
    (void)in_sizes; (void)n_in; (void)out_size; (void)ws_size;
    const float* x    = (const float*)d_in[0];
    const float* pew  = (const float*)d_in[1];
    const float* peb  = (const float*)d_in[2];
    const float* cls  = (const float*)d_in[3];
    const float* n1w  = (const float*)d_in[4];
    const float* n1b  = (const float*)d_in[5];
    const float* qkvw = (const float*)d_in[6];
    const float* qb   = (const float*)d_in[7];
    const float* vb   = (const float*)d_in[8];
    const float* rpt  = (const float*)d_in[9];
    const float* pw   = (const float*)d_in[10];
    const float* pb   = (const float*)d_in[11];
    const float* n2w  = (const float*)d_in[12];
    const float* n2b  = (const float*)d_in[13];
    const float* f1w  = (const float*)d_in[14];
    const float* f1b  = (const float*)d_in[15];
    const float* f2w  = (const float*)d_in[16];
    const float* f2b_ = (const float*)d_in[17];
    const float* nfw  = (const float*)d_in[18];
    const float* nfb  = (const float*)d_in[19];

    // workspace (floats): h | y(bf16) | un | wbuf(bf16) | qbias[12]  ~= 82 MB
    float* ws = (float*)d_ws;
    float* h     = ws;                                   // 4,841,472 f32
    u16*   y     = (u16*)(ws + 4841472);                 // bf16 [M,768]
    float* un    = ws + 4841472 + 2420736;               // 9,682,944 f32 union
    u16*   wbuf  = (u16*)(un + 9682944);                 // 7,077,888 bf16
    float* qbias = (float*)(wbuf + 7077888);             // 12*2304 f32
    u16*   qkvb   = (u16*)un;                            // bf16 [M,2304]
    u16*   hidden = (u16*)un;                            // bf16 [M,3072]
    u16*   pmat   = (u16*)un;                            // bf16 [6272,768]
    float* pout   = un + 4816896;                        // f32  [6272,768]

    const int MT = (M_ + 127) / 128;  // 50

    // patch embed
    cvt_k<<<288, 256, 0, stream>>>(pew, wbuf, SEG1 / 8);
    patchify_k<<<(MP_ * DIM_ + 255) / 256, 256, 0, stream>>>(x, pmat);
    qkvbias_all_k<<<(DEPTH_ * QKV_ + 255) / 256, 256, 0, stream>>>(qb, vb, qbias);
    gemm_bt<0, 0><<<dim3(6, 49), 512, 0, stream>>>(pmat, wbuf, peb, nullptr, pout,
                                                   MP_, DIM_, DIM_);
    build_tokens_k<<<(M_ * DIM_ + 255) / 256, 256, 0, stream>>>(pout, cls, h);

    for (int l = 0; l < 12; l++) {
        layernorm_k<1><<<M_, 256, 0, stream>>>(h, n1w + l * DIM_, n1b + l * DIM_, y);
        cvt4_k<<<3456, 256, 0, stream>>>(qkvw + (size_t)l * SEG0, pw + (size_t)l * SEG1,
                                         f1w + (size_t)l * SEG2, f2w + (size_t)l * SEG3, wbuf);
        gemm_bt<0, 1><<<dim3(18, MT), 512, 0, stream>>>(y, wbuf, qbias + l * QKV_, nullptr,
                                                        qkvb, M_, QKV_, DIM_);
        attn3_k<<<dim3(384, 4), 256, 0, stream>>>(qkvb, rpt + (size_t)l * NRD_ * HEADS_, y);
        gemm_bt<0, 0><<<dim3(6, MT), 512, 0, stream>>>(y, wbuf + SEG0, pb + l * DIM_, h, h,
                                                       M_, DIM_, DIM_);
        layernorm_k<1><<<M_, 256, 0, stream>>>(h, n2w + l * DIM_, n2b + l * DIM_, y);
        gemm_bt<1, 1><<<dim3(24, MT), 512, 0, stream>>>(y, wbuf + SEG0 + SEG1, f1b + l * FF_,
                                                        nullptr, hidden, M_, FF_, DIM_);
        gemm_bt<0, 0><<<dim3(6, MT), 512, 0, stream>>>(hidden, wbuf + SEG0 + SEG1 + SEG2,
                                                       f2b_ + l * DIM_, h, h, M_, DIM_, FF_);
    }
    layernorm_k<0><<<M_, 256, 0, stream>>>(h, nfw, nfb, d_out);
}